// Round 13
// baseline (71.413 us; speedup 1.0000x reference)
//
#include <hip/hip_runtime.h>
#include <hip/hip_fp16.h>

// Problem constants (match reference)
constexpr int B  = 4;
constexpr int C  = 3;
constexpr int F  = 5;
constexpr int HO = 256;
constexpr int WO = 256;
constexpr int HI = HO + F - 1; // 260
constexpr int WI = WO + F - 1; // 260
constexpr int P  = HO * WO;    // 65536 pixels per (b, map)
constexpr int FF = F * F;      // 25
constexpr int PI = HI * WI;    // 67600 input pixels per (b, c)

// Block = 512 threads = 8 waves; patch (y0..y0+3, x0..x0+63).
// Wave w: y-row y0+(w>>1), tap-half (w&1): k in [0,12) or [12,25).
// ALL streaming values for the wave's taps (<=13 x 3 + v/h 8 = 47 regs) are
// loaded up-front BEFORE tile staging; the staging barrier's vmcnt(0) drain
// completes them under staging latency. Tap loop has ZERO VMEM: pure
// VALU + LDS gathers. Needs 128-VGPR budget -> __launch_bounds__(512, 4)
// (R3/R5's spill trap was the 64-cap; check WRITE_SIZE stays ~3 MB).
// Tile: rows [y0-7, y0+13] (21) x cols [x0-7, x0+72] (80), fp16 uint2.
constexpr int TROWS = 21;
constexpr int TCOLS = 80;
constexpr int TSTRIDE = 81;            // 8B units
constexpr int TN = TROWS * TCOLS;      // 1680 entries
constexpr int AMAX = (TROWS - 2) * TSTRIDE + (TCOLS - 2);

__device__ __forceinline__ uint2 pack3(float a, float b, float c) {
    __half2 ab = __floats2half2_rn(a, b);
    __half2 cz = __floats2half2_rn(c, 0.0f);
    uint2 r;
    r.x = *reinterpret_cast<const unsigned int*>(&ab);
    r.y = *reinterpret_cast<const unsigned int*>(&cz);
    return r;
}

__device__ __forceinline__ void fmacc(uint2 v, float w,
                                      float& a0, float& a1, float& a2) {
    __half2 ab = *reinterpret_cast<const __half2*>(&v.x);
    __half2 cz = *reinterpret_cast<const __half2*>(&v.y);
    // (float)half * f32 + f32 acc -> v_fma_mix_f32
    a0 += __half2float(__low2half(ab))  * w;
    a1 += __half2float(__high2half(ab)) * w;
    a2 += __half2float(__low2half(cz))  * w;
}

// ---- Phase 1: issue every streaming load for this wave's taps ----
// All array indices are compile-time constants (runtime-indexed locals go
// to scratch). IB = K0/F.
template <int K0, int NK>
__device__ __forceinline__ void load_streams(
    const float* __restrict__ offYb, const float* __restrict__ offXb,
    const float* __restrict__ maskb,
    const float* __restrict__ vb, const float* __restrict__ hb,
    float (&oy)[13], float (&ox)[13], float (&mk)[13],
    float (&vv)[3], float (&hh)[5])
{
#pragma unroll
    for (int q = 0; q < NK; ++q) oy[q] = offYb[(K0 + q) * P];
#pragma unroll
    for (int q = 0; q < NK; ++q) ox[q] = offXb[(K0 + q) * P];
#pragma unroll
    for (int q = 0; q < NK; ++q) mk[q] = maskb[(K0 + q) * P];
    constexpr int IB = K0 / F;
#pragma unroll
    for (int q = 0; q < 3; ++q) vv[q] = vb[(IB + q) * P];
#pragma unroll
    for (int q = 0; q < 5; ++q) hh[q] = hb[q * P];
}

// ---- Phase 2: compute NK taps from registers + LDS tile ----
template <int K0, int NK>
__device__ __forceinline__ void compute_taps(
    const uint2* __restrict__ tileq,
    const float* __restrict__ in0, const float* __restrict__ in1,
    const float* __restrict__ in2,
    const float (&oy)[13], const float (&ox)[13], const float (&mk)[13],
    const float (&vv)[3], const float (&hh)[5],
    int x, int y, int ry0, int cx0,
    float& acc0, float& acc1, float& acc2)
{
    constexpr int IB = K0 / F;
#pragma unroll
    for (int q = 0; q < NK; ++q) {
        constexpr_int:
        const int k = K0 + q;        // constant
        const int i = k / F;         // constant
        const int j = k % F;         // constant

        // px = clip(offY + x + j - half + 1, 0, WI-1); half = 2
        float px = fminf(fmaxf(oy[q] + (float)(x + j - 1), 0.0f), (float)(WI - 1));
        float py = fminf(fmaxf(ox[q] + (float)(y + i - 1), 0.0f), (float)(HI - 1));

        float lf = floorf(px);
        float tf = floorf(py);
        int l  = (int)lf;
        int t_ = (int)tf;
        float wx = 1.0f - (px - lf);
        float wy = 1.0f - (py - tf);

        // Bilinear identity: clamped edge => r/bottom weights exactly 0,
        // so always read l+1 / t+1 (tile has the +1 margin).
        float w   = vv[i - IB] * hh[j] * mk[q];
        float wyw = wy * w;
        float wbw = w - wyw;
        float wtl = wx * wyw;
        float wtr = wyw - wtl;
        float wbl = wx * wbw;
        float wbr = wbw - wbl;

        int lt = t_ - ry0;
        int ll = l - cx0;
        bool ok = ((unsigned)lt <= TROWS - 2) & ((unsigned)ll <= TCOLS - 2);

        int a = min(max(lt * TSTRIDE + ll, 0), AMAX); // safe for !ok lanes

        uint2 g_tl = tileq[a];
        uint2 g_tr = tileq[a + 1];
        uint2 g_bl = tileq[a + TSTRIDE];
        uint2 g_br = tileq[a + TSTRIDE + 1];

        // rare fallback: offset beyond tile margin (~1e-9/sample)
        if (__any(!ok)) {
            if (!ok) {
                int r  = min(l + 1, WI - 1);
                int bt = min(t_ + 1, HI - 1);
                int o_tl = t_ * WI + l,  o_tr = t_ * WI + r;
                int o_bl = bt * WI + l,  o_br = bt * WI + r;
                g_tl = pack3(in0[o_tl], in1[o_tl], in2[o_tl]);
                g_tr = pack3(in0[o_tr], in1[o_tr], in2[o_tr]);
                g_bl = pack3(in0[o_bl], in1[o_bl], in2[o_bl]);
                g_br = pack3(in0[o_br], in1[o_br], in2[o_br]);
            }
        }

        fmacc(g_tl, wtl, acc0, acc1, acc2);
        fmacc(g_tr, wtr, acc0, acc1, acc2);
        fmacc(g_bl, wbl, acc0, acc1, acc2);
        fmacc(g_br, wbr, acc0, acc1, acc2);
    }
}

__global__ __launch_bounds__(512, 4) void dsepconv_kernel(
    const float* __restrict__ inp,   // (B, C, HI, WI)
    const float* __restrict__ vert,  // (B, F, HO, WO)
    const float* __restrict__ horz,  // (B, F, HO, WO)
    const float* __restrict__ offX,  // -> py (vertical), per reference
    const float* __restrict__ offY,  // -> px (horizontal), per reference
    const float* __restrict__ mask,  // (B, F*F, HO, WO)
    float* __restrict__ out)         // (B, C, HO, WO)
{
    __shared__ uint2 tileq[TROWS * TSTRIDE];  // 13,608 B
    __shared__ float red[4][3][64];           // 3,072 B

    const int tid  = threadIdx.x;
    const int lane = tid & 63;
    const int wave = tid >> 6;                 // 0..7
    const int wrow = wave >> 1;                // 0..3: y-row in patch
    const int half = wave & 1;                 // 0..1: tap half

    // Grid: bx = b*256 + yblk*4 + xblk
    const int bx   = blockIdx.x;
    const int x0   = (bx & 3) * 64;
    const int y0   = ((bx >> 2) & 63) * 4;
    const int b    = bx >> 8;

    const float* in0 = inp + (size_t)b * C * PI;
    const float* in1 = in0 + PI;
    const float* in2 = in1 + PI;

    const int x   = x0 + lane;
    const int y   = y0 + wrow;
    const int pix = y * WO + x;

    const float* offXb = offX + (size_t)b * FF * P + pix;
    const float* offYb = offY + (size_t)b * FF * P + pix;
    const float* maskb = mask + (size_t)b * FF * P + pix;
    const float* vb    = vert + (size_t)b * F * P + pix;
    const float* hb    = horz + (size_t)b * F * P + pix;

    // ---- Phase 1: all streaming loads in flight BEFORE staging ----
    float oy[13], ox[13], mk[13], vv[3], hh[5];
    if (half == 0) {
        load_streams<0, 12>(offYb, offXb, maskb, vb, hb, oy, ox, mk, vv, hh);
    } else {
        load_streams<12, 13>(offYb, offXb, maskb, vb, hb, oy, ox, mk, vv, hh);
    }

    // ---- Stage tile: rows [y0-7, y0+13], cols [x0-7, x0+72] ----
    const int ry0 = y0 - 7;
    const int cx0 = x0 - 7;
#pragma unroll 1
    for (int e = tid; e < TN; e += 512) {
        int trow = e / TCOLS;
        int tcol = e - trow * TCOLS;
        int gy = min(max(ry0 + trow, 0), HI - 1);
        int gx = min(max(cx0 + tcol, 0), WI - 1);
        int g = gy * WI + gx;
        tileq[trow * TSTRIDE + tcol] = pack3(in0[g], in1[g], in2[g]);
    }
    __syncthreads();   // vmcnt(0) drain also completes the stream prefetch

    float acc0 = 0.f, acc1 = 0.f, acc2 = 0.f;

    // ---- Phase 2: tap loop with zero VMEM ----
    if (half == 0) {
        compute_taps<0, 12>(tileq, in0, in1, in2, oy, ox, mk, vv, hh,
                            x, y, ry0, cx0, acc0, acc1, acc2);
    } else {
        compute_taps<12, 13>(tileq, in0, in1, in2, oy, ox, mk, vv, hh,
                             x, y, ry0, cx0, acc0, acc1, acc2);
    }

    // ---- Combine the two tap-halves per row ----
    if (half) {
        red[wrow][0][lane] = acc0;
        red[wrow][1][lane] = acc1;
        red[wrow][2][lane] = acc2;
    }
    __syncthreads();

    if (!half) {
        float* ob = out + (size_t)b * C * P + pix;
        ob[0]     = acc0 + red[wrow][0][lane];
        ob[P]     = acc1 + red[wrow][1][lane];
        ob[2 * P] = acc2 + red[wrow][2][lane];
    }
}

extern "C" void kernel_launch(void* const* d_in, const int* in_sizes, int n_in,
                              void* d_out, int out_size, void* d_ws, size_t ws_size,
                              hipStream_t stream) {
    const float* inp  = (const float*)d_in[0];
    const float* vert = (const float*)d_in[1];
    const float* horz = (const float*)d_in[2];
    const float* offX = (const float*)d_in[3];
    const float* offY = (const float*)d_in[4];
    const float* mask = (const float*)d_in[5];
    float* out = (float*)d_out;

    // grid: B * (HO/4) * (WO/64) = 4 * 64 * 4 = 1024 blocks, 512 thr each
    dim3 block(512);
    dim3 grid(B * (HO / 4) * (WO / 64));
    dsepconv_kernel<<<grid, block, 0, stream>>>(inp, vert, horz, offX, offY, mask, out);
}

// Round 14
// 66.606 us; speedup vs baseline: 1.0722x; 1.0722x over previous
//
#include <hip/hip_runtime.h>
#include <hip/hip_fp16.h>

// Problem constants (match reference)
constexpr int B  = 4;
constexpr int C  = 3;
constexpr int F  = 5;
constexpr int HO = 256;
constexpr int WO = 256;
constexpr int HI = HO + F - 1; // 260
constexpr int WI = WO + F - 1; // 260
constexpr int P  = HO * WO;    // 65536 pixels per (b, map)
constexpr int FF = F * F;      // 25
constexpr int PI = HI * WI;    // 67600 input pixels per (b, c)

// Block = 512 threads = 8 waves; patch (y0..y0+3, x0..x0+63).
// Wave w: y-row y0+(w>>1), tap-half (w&1): k in [0,12) or [12,25).
// 2-stage tap pipeline: stageA(k) computes coords + issues the 4 LDS
// gathers; stageB(k-1) does weights + FMAs — the ~120cy ds_read wait of
// tap k hides under tap k-1's VALU. Streams stay 1-deep prefetched (R11).
// Tile: rows [y0-7, y0+13] (21) x cols [x0-7, x0+72] (80), fp16 uint2.
// TSTRIDE = 85 (mod 16 = 5): bank-pair = (c + 5r) mod 16, so the common
// jitter collisions (dr, dc) = (n, -n) of the 81-stride layout vanish.
constexpr int TROWS = 21;
constexpr int TCOLS = 80;
constexpr int TSTRIDE = 85;            // 8B units
constexpr int TN = TROWS * TCOLS;      // 1680 entries to stage
constexpr int AMAX = (TROWS - 2) * TSTRIDE + (TCOLS - 2); // 1693

__device__ __forceinline__ uint2 pack3(float a, float b, float c) {
    __half2 ab = __floats2half2_rn(a, b);
    __half2 cz = __floats2half2_rn(c, 0.0f);
    uint2 r;
    r.x = *reinterpret_cast<const unsigned int*>(&ab);
    r.y = *reinterpret_cast<const unsigned int*>(&cz);
    return r;
}

__device__ __forceinline__ void fmacc(uint2 v, float w,
                                      float& a0, float& a1, float& a2) {
    __half2 ab = *reinterpret_cast<const __half2*>(&v.x);
    __half2 cz = *reinterpret_cast<const __half2*>(&v.y);
    // (float)half * f32 + f32 acc -> v_fma_mix_f32
    a0 += __half2float(__low2half(ab))  * w;
    a1 += __half2float(__high2half(ab)) * w;
    a2 += __half2float(__low2half(cz))  * w;
}

struct Tap {                 // all fields statically addressed -> registers
    float wx, wy, w;
    int   l, t;
    bool  ok;
    uint2 g0, g1, g2, g3;
};

__device__ __forceinline__ void loadStreams(
    int k, const float* __restrict__ offYb, const float* __restrict__ offXb,
    const float* __restrict__ maskb, const float* __restrict__ vb,
    const float* __restrict__ hb,
    float& oy, float& ox, float& m, float& h, float& v)
{
    int i = k / F;
    int j = k - i * F;
    oy = offYb[(size_t)k * P];
    ox = offXb[(size_t)k * P];
    m  = maskb[(size_t)k * P];
    h  = hb[j * P];   // L1-hot (5 distinct lines)
    v  = vb[i * P];   // L1-hot
}

__device__ __forceinline__ void stageA(
    int k, Tap& S, float oy, float ox, float m, float h, float v,
    const uint2* __restrict__ tileq, int x, int y, int ry0, int cx0)
{
    int i = k / F;
    int j = k - i * F;
    // px = clip(offY + x + j - half + 1, 0, WI-1); half = 2
    float px = fminf(fmaxf(oy + (float)(x + j - 1), 0.0f), (float)(WI - 1));
    float py = fminf(fmaxf(ox + (float)(y + i - 1), 0.0f), (float)(HI - 1));
    float lf = floorf(px);
    float tf = floorf(py);
    S.l  = (int)lf;
    S.t  = (int)tf;
    S.wx = 1.0f - (px - lf);
    S.wy = 1.0f - (py - tf);
    S.w  = v * h * m;
    int lt = S.t - ry0;
    int ll = S.l - cx0;
    S.ok = ((unsigned)lt <= TROWS - 2) & ((unsigned)ll <= TCOLS - 2);
    int a = min(max(lt * TSTRIDE + ll, 0), AMAX); // safe for !ok lanes
    S.g0 = tileq[a];
    S.g1 = tileq[a + 1];
    S.g2 = tileq[a + TSTRIDE];
    S.g3 = tileq[a + TSTRIDE + 1];
}

__device__ __forceinline__ void stageB(
    Tap& S, const float* __restrict__ in0, const float* __restrict__ in1,
    const float* __restrict__ in2, float& acc0, float& acc1, float& acc2)
{
    // rare fallback: offset beyond tile margin (~1e-9/sample)
    if (__any(!S.ok)) {
        if (!S.ok) {
            int r  = min(S.l + 1, WI - 1);
            int bt = min(S.t + 1, HI - 1);
            int o_tl = S.t * WI + S.l, o_tr = S.t * WI + r;
            int o_bl = bt * WI + S.l,  o_br = bt * WI + r;
            S.g0 = pack3(in0[o_tl], in1[o_tl], in2[o_tl]);
            S.g1 = pack3(in0[o_tr], in1[o_tr], in2[o_tr]);
            S.g2 = pack3(in0[o_bl], in1[o_bl], in2[o_bl]);
            S.g3 = pack3(in0[o_br], in1[o_br], in2[o_br]);
        }
    }
    // Bilinear identity: clamped edge => r/bottom weights exactly 0.
    float wyw = S.wy * S.w;
    float wbw = S.w - wyw;
    float wtl = S.wx * wyw;
    float wtr = wyw - wtl;
    float wbl = S.wx * wbw;
    float wbr = wbw - wbl;
    fmacc(S.g0, wtl, acc0, acc1, acc2);
    fmacc(S.g1, wtr, acc0, acc1, acc2);
    fmacc(S.g2, wbl, acc0, acc1, acc2);
    fmacc(S.g3, wbr, acc0, acc1, acc2);
}

__global__ __launch_bounds__(512, 8) void dsepconv_kernel(
    const float* __restrict__ inp,   // (B, C, HI, WI)
    const float* __restrict__ vert,  // (B, F, HO, WO)
    const float* __restrict__ horz,  // (B, F, HO, WO)
    const float* __restrict__ offX,  // -> py (vertical), per reference
    const float* __restrict__ offY,  // -> px (horizontal), per reference
    const float* __restrict__ mask,  // (B, F*F, HO, WO)
    float* __restrict__ out)         // (B, C, HO, WO)
{
    __shared__ uint2 tileq[TROWS * TSTRIDE];  // 14,280 B
    __shared__ float red[4][3][64];           // 3,072 B

    const int tid  = threadIdx.x;
    const int lane = tid & 63;
    const int wave = tid >> 6;                 // 0..7
    const int wrow = wave >> 1;                // 0..3: y-row in patch
    const int half = wave & 1;                 // 0..1: tap half

    // Grid: bx = b*256 + yblk*4 + xblk
    const int bx   = blockIdx.x;
    const int x0   = (bx & 3) * 64;
    const int y0   = ((bx >> 2) & 63) * 4;
    const int b    = bx >> 8;

    const float* in0 = inp + (size_t)b * C * PI;
    const float* in1 = in0 + PI;
    const float* in2 = in1 + PI;

    const int x   = x0 + lane;
    const int y   = y0 + wrow;
    const int pix = y * WO + x;

    const float* offXb = offX + (size_t)b * FF * P + pix;
    const float* offYb = offY + (size_t)b * FF * P + pix;
    const float* maskb = mask + (size_t)b * FF * P + pix;
    const float* vb    = vert + (size_t)b * F * P + pix;
    const float* hb    = horz + (size_t)b * F * P + pix;

    const int k0   = half ? 12 : 0;
    const int k1   = half ? 25 : 12;
    const int klast = k1 - 1;

    // ---- Prefetch first tap's streams (drained by the staging barrier) ----
    float oy, ox, m, h, v, oy_n, ox_n, m_n, h_n, v_n;
    loadStreams(k0, offYb, offXb, maskb, vb, hb, oy, ox, m, h, v);

    // ---- Stage tile: rows [y0-7, y0+13], cols [x0-7, x0+72] ----
    const int ry0 = y0 - 7;
    const int cx0 = x0 - 7;
#pragma unroll 1
    for (int e = tid; e < TN; e += 512) {
        int trow = e / TCOLS;
        int tcol = e - trow * TCOLS;
        int gy = min(max(ry0 + trow, 0), HI - 1);
        int gx = min(max(cx0 + tcol, 0), WI - 1);
        int g = gy * WI + gx;
        tileq[trow * TSTRIDE + tcol] = pack3(in0[g], in1[g], in2[g]);
    }
    __syncthreads();   // vmcnt(0) drain also completes the stream prefetch

    float acc0 = 0.f, acc1 = 0.f, acc2 = 0.f;
    Tap SA, SB;

    // ---- software-pipelined tap loop: A(k) overlaps B(k-1) ----
    loadStreams(min(k0 + 1, klast), offYb, offXb, maskb, vb, hb,
                oy_n, ox_n, m_n, h_n, v_n);
    stageA(k0, SA, oy, ox, m, h, v, tileq, x, y, ry0, cx0);
    oy = oy_n; ox = ox_n; m = m_n; h = h_n; v = v_n;

    int k = k0 + 1;
#pragma unroll 1
    for (; k + 1 < k1; k += 2) {
        loadStreams(min(k + 1, klast), offYb, offXb, maskb, vb, hb,
                    oy_n, ox_n, m_n, h_n, v_n);
        stageA(k, SB, oy, ox, m, h, v, tileq, x, y, ry0, cx0);
        oy = oy_n; ox = ox_n; m = m_n; h = h_n; v = v_n;
        stageB(SA, in0, in1, in2, acc0, acc1, acc2);

        loadStreams(min(k + 2, klast), offYb, offXb, maskb, vb, hb,
                    oy_n, ox_n, m_n, h_n, v_n);
        stageA(k + 1, SA, oy, ox, m, h, v, tileq, x, y, ry0, cx0);
        oy = oy_n; ox = ox_n; m = m_n; h = h_n; v = v_n;
        stageB(SB, in0, in1, in2, acc0, acc1, acc2);
    }
    if (k < k1) {      // even NK tail: one A + two B
        stageA(k, SB, oy, ox, m, h, v, tileq, x, y, ry0, cx0);
        stageB(SA, in0, in1, in2, acc0, acc1, acc2);
        stageB(SB, in0, in1, in2, acc0, acc1, acc2);
    } else {           // odd NK tail
        stageB(SA, in0, in1, in2, acc0, acc1, acc2);
    }

    // ---- Combine the two tap-halves per row ----
    if (half) {
        red[wrow][0][lane] = acc0;
        red[wrow][1][lane] = acc1;
        red[wrow][2][lane] = acc2;
    }
    __syncthreads();

    if (!half) {
        float* ob = out + (size_t)b * C * P + pix;
        ob[0]     = acc0 + red[wrow][0][lane];
        ob[P]     = acc1 + red[wrow][1][lane];
        ob[2 * P] = acc2 + red[wrow][2][lane];
    }
}

extern "C" void kernel_launch(void* const* d_in, const int* in_sizes, int n_in,
                              void* d_out, int out_size, void* d_ws, size_t ws_size,
                              hipStream_t stream) {
    const float* inp  = (const float*)d_in[0];
    const float* vert = (const float*)d_in[1];
    const float* horz = (const float*)d_in[2];
    const float* offX = (const float*)d_in[3];
    const float* offY = (const float*)d_in[4];
    const float* mask = (const float*)d_in[5];
    float* out = (float*)d_out;

    // grid: B * (HO/4) * (WO/64) = 4 * 64 * 4 = 1024 blocks, 512 thr each
    dim3 block(512);
    dim3 grid(B * (HO / 4) * (WO / 64));
    dsepconv_kernel<<<grid, block, 0, stream>>>(inp, vert, horz, offX, offY, mask, out);
}

// Round 15
// 25.638 us; speedup vs baseline: 2.7855x; 2.5980x over previous
//
#include <hip/hip_runtime.h>
#include <hip/hip_fp16.h>

// Problem constants (match reference)
constexpr int B  = 4;
constexpr int C  = 3;
constexpr int F  = 5;
constexpr int HO = 256;
constexpr int WO = 256;
constexpr int HI = HO + F - 1; // 260
constexpr int WI = WO + F - 1; // 260
constexpr int P  = HO * WO;    // 65536 pixels per (b, map)
constexpr int FF = F * F;      // 25
constexpr int PI = HI * WI;    // 67600 input pixels per (b, c)

// R11 structure (best: 26.15us) with ONE isolated change: TSTRIDE 81 -> 85.
// Bank-group = (2*(lt*TSTRIDE+ll)) mod 32. 81 = 1 mod 16 makes the common
// bilinear jitter diagonal (dr,dc)=(n,-n) collide; 85 = 5 mod 16 requires
// 5*dr+dc = 0 mod 16 (only (3,-1)-type in jitter range, ~5x rarer).
// Block = 512 threads = 8 waves; patch (y0..y0+3, x0..x0+63).
// Wave w: y-row y0+(w>>1), tap-half (w&1): k in [0,12) or [12,25).
// 1-deep stream prefetch (R11). Tap loop otherwise load-and-use (no big
// per-thread state: R3/R5/R13/R14 all spilled when widening it).
constexpr int TROWS = 21;
constexpr int TCOLS = 80;
constexpr int TSTRIDE = 85;            // 8B units (the experiment)
constexpr int TN = TROWS * TCOLS;      // 1680 entries to stage
constexpr int AMAX = (TROWS - 2) * TSTRIDE + (TCOLS - 2); // 1693

__device__ __forceinline__ uint2 pack3(float a, float b, float c) {
    __half2 ab = __floats2half2_rn(a, b);
    __half2 cz = __floats2half2_rn(c, 0.0f);
    uint2 r;
    r.x = *reinterpret_cast<const unsigned int*>(&ab);
    r.y = *reinterpret_cast<const unsigned int*>(&cz);
    return r;
}

__device__ __forceinline__ void fmacc(uint2 v, float w,
                                      float& a0, float& a1, float& a2) {
    __half2 ab = *reinterpret_cast<const __half2*>(&v.x);
    __half2 cz = *reinterpret_cast<const __half2*>(&v.y);
    // (float)half * f32 + f32 acc -> v_fma_mix_f32
    a0 += __half2float(__low2half(ab))  * w;
    a1 += __half2float(__high2half(ab)) * w;
    a2 += __half2float(__low2half(cz))  * w;
}

__global__ __launch_bounds__(512, 8) void dsepconv_kernel(
    const float* __restrict__ inp,   // (B, C, HI, WI)
    const float* __restrict__ vert,  // (B, F, HO, WO)
    const float* __restrict__ horz,  // (B, F, HO, WO)
    const float* __restrict__ offX,  // -> py (vertical), per reference
    const float* __restrict__ offY,  // -> px (horizontal), per reference
    const float* __restrict__ mask,  // (B, F*F, HO, WO)
    float* __restrict__ out)         // (B, C, HO, WO)
{
    __shared__ uint2 tileq[TROWS * TSTRIDE];  // 14,280 B
    __shared__ float red[4][3][64];           // 3,072 B

    const int tid  = threadIdx.x;
    const int lane = tid & 63;
    const int wave = tid >> 6;                 // 0..7
    const int wrow = wave >> 1;                // 0..3: y-row in patch
    const int half = wave & 1;                 // 0..1: tap half

    // Grid: bx = b*256 + yblk*4 + xblk
    const int bx   = blockIdx.x;
    const int x0   = (bx & 3) * 64;
    const int y0   = ((bx >> 2) & 63) * 4;
    const int b    = bx >> 8;

    const float* in0 = inp + (size_t)b * C * PI;
    const float* in1 = in0 + PI;
    const float* in2 = in1 + PI;

    const int x   = x0 + lane;
    const int y   = y0 + wrow;
    const int pix = y * WO + x;

    const float* offXb = offX + (size_t)b * FF * P + pix;
    const float* offYb = offY + (size_t)b * FF * P + pix;
    const float* maskb = mask + (size_t)b * FF * P + pix;
    const float* vb    = vert + (size_t)b * F * P + pix;
    const float* hb    = horz + (size_t)b * F * P + pix;

    const int k0 = half ? 12 : 0;
    const int k1 = half ? 25 : 12;

    // ---- Prefetch first tap's streaming values (completes under barrier) ----
    float oy, ox, m, h, v;
    {
        const int i = k0 / F, j = k0 - (k0 / F) * F;
        oy = offYb[k0 * P];
        ox = offXb[k0 * P];
        m  = maskb[k0 * P];
        h  = hb[j * P];
        v  = vb[i * P];
    }

    // ---- Stage tile: rows [y0-7, y0+13], cols [x0-7, x0+72] ----
    const int ry0 = y0 - 7;
    const int cx0 = x0 - 7;
#pragma unroll 1
    for (int e = tid; e < TN; e += 512) {
        int trow = e / TCOLS;
        int tcol = e - trow * TCOLS;
        int gy = min(max(ry0 + trow, 0), HI - 1);
        int gx = min(max(cx0 + tcol, 0), WI - 1);
        int g = gy * WI + gx;
        tileq[trow * TSTRIDE + tcol] = pack3(in0[g], in1[g], in2[g]);
    }
    __syncthreads();

    float acc0 = 0.f, acc1 = 0.f, acc2 = 0.f;

#pragma unroll 1
    for (int k = k0; k < k1; ++k) {
        const int i = k / F;
        const int j = k - i * F;

        // ---- issue NEXT tap's streaming loads (overlap with this compute) ----
        const int kn = (k + 1 < k1) ? k + 1 : k;   // last iter: harmless reload
        const int in_ = kn / F;
        const int jn  = kn - in_ * F;
        float oy_n = offYb[kn * P];
        float ox_n = offXb[kn * P];
        float m_n  = maskb[kn * P];
        float h_n  = hb[jn * P];
        float v_n  = vb[in_ * P];

        // ---- compute current tap from registers ----
        // px = clip(offY + x + j - half + 1, 0, WI-1); half = 2
        float px = fminf(fmaxf(oy + (float)(x + j - 1), 0.0f), (float)(WI - 1));
        float py = fminf(fmaxf(ox + (float)(y + i - 1), 0.0f), (float)(HI - 1));

        float lf = floorf(px);
        float tf = floorf(py);
        int l = (int)lf;
        int t = (int)tf;
        float wx = 1.0f - (px - lf);
        float wy = 1.0f - (py - tf);

        // Bilinear identity: clamped edge => r/bottom weights exactly 0,
        // so always read l+1 / t+1 (tile has the +1 margin).
        float w   = v * h * m;
        float wyw = wy * w;
        float wbw = w - wyw;
        float wtl = wx * wyw;
        float wtr = wyw - wtl;
        float wbl = wx * wbw;
        float wbr = wbw - wbl;

        int lt = t - ry0;
        int ll = l - cx0;
        bool ok = ((unsigned)lt <= TROWS - 2) & ((unsigned)ll <= TCOLS - 2);

        int a = min(max(lt * TSTRIDE + ll, 0), AMAX); // safe for !ok lanes

        uint2 g_tl = tileq[a];
        uint2 g_tr = tileq[a + 1];
        uint2 g_bl = tileq[a + TSTRIDE];
        uint2 g_br = tileq[a + TSTRIDE + 1];

        // rare fallback: offset beyond tile margin (~1e-9/sample)
        if (__any(!ok)) {
            if (!ok) {
                int r  = min(l + 1, WI - 1);
                int bt = min(t + 1, HI - 1);
                int o_tl = t * WI + l,  o_tr = t * WI + r;
                int o_bl = bt * WI + l, o_br = bt * WI + r;
                g_tl = pack3(in0[o_tl], in1[o_tl], in2[o_tl]);
                g_tr = pack3(in0[o_tr], in1[o_tr], in2[o_tr]);
                g_bl = pack3(in0[o_bl], in1[o_bl], in2[o_bl]);
                g_br = pack3(in0[o_br], in1[o_br], in2[o_br]);
            }
        }

        fmacc(g_tl, wtl, acc0, acc1, acc2);
        fmacc(g_tr, wtr, acc0, acc1, acc2);
        fmacc(g_bl, wbl, acc0, acc1, acc2);
        fmacc(g_br, wbr, acc0, acc1, acc2);

        // ---- rotate pipeline ----
        oy = oy_n; ox = ox_n; m = m_n; h = h_n; v = v_n;
    }

    // ---- Combine the two tap-halves per row ----
    if (half) {
        red[wrow][0][lane] = acc0;
        red[wrow][1][lane] = acc1;
        red[wrow][2][lane] = acc2;
    }
    __syncthreads();

    if (!half) {
        float* ob = out + (size_t)b * C * P + pix;
        ob[0]     = acc0 + red[wrow][0][lane];
        ob[P]     = acc1 + red[wrow][1][lane];
        ob[2 * P] = acc2 + red[wrow][2][lane];
    }
}

extern "C" void kernel_launch(void* const* d_in, const int* in_sizes, int n_in,
                              void* d_out, int out_size, void* d_ws, size_t ws_size,
                              hipStream_t stream) {
    const float* inp  = (const float*)d_in[0];
    const float* vert = (const float*)d_in[1];
    const float* horz = (const float*)d_in[2];
    const float* offX = (const float*)d_in[3];
    const float* offY = (const float*)d_in[4];
    const float* mask = (const float*)d_in[5];
    float* out = (float*)d_out;

    // grid: B * (HO/4) * (WO/64) = 4 * 64 * 4 = 1024 blocks, 512 thr each
    dim3 block(512);
    dim3 grid(B * (HO / 4) * (WO / 64));
    dsepconv_kernel<<<grid, block, 0, stream>>>(inp, vert, horz, offX, offY, mask, out);
}

// Round 16
// 24.751 us; speedup vs baseline: 2.8853x; 1.0358x over previous
//
#include <hip/hip_runtime.h>
#include <hip/hip_fp16.h>

// Problem constants (match reference)
constexpr int B  = 4;
constexpr int C  = 3;
constexpr int F  = 5;
constexpr int HO = 256;
constexpr int WO = 256;
constexpr int HI = HO + F - 1; // 260
constexpr int WI = WO + F - 1; // 260
constexpr int P  = HO * WO;    // 65536 pixels per (b, map)
constexpr int FF = F * F;      // 25
constexpr int PI = HI * WI;    // 67600 input pixels per (b, c)

// R16: 2 adjacent pixels per thread (x, x+1).
// Block = 256 threads = 4 waves: wave = (row in {0,1}) x (tap-half in {0,1}).
// Patch = 128 px wide x 2 rows. All streaming loads are float2 (1 instr / 2 px),
// per-tap overhead amortized over 2 px, 8 ds_reads per tap issue before 24 FMAs.
// Persistent state stays small (6 acc + 10 prefetch regs) -> no spill at 256-thr
// blocks (the 512-thread 64-VGPR pin was the R3/R5/R13/R14 spill cause).
// Tile: rows [y0-7, y0+11] (19) x cols [x0-7, x0+137] (145), fp16 uint2.
// TSTRIDE = 149 (mod 16 = 5): R15's bank-decollision result carried over.
constexpr int TROWS = 19;
constexpr int TCOLS = 145;
constexpr int TSTRIDE = 149;           // 8B units
constexpr int TN = TROWS * TCOLS;      // 2755 entries to stage
constexpr int AMAX = (TROWS - 2) * TSTRIDE + (TCOLS - 2); // 2676

__device__ __forceinline__ float2 ld2(const float* p) {
    return *reinterpret_cast<const float2*>(p);
}

__device__ __forceinline__ uint2 pack3(float a, float b, float c) {
    __half2 ab = __floats2half2_rn(a, b);
    __half2 cz = __floats2half2_rn(c, 0.0f);
    uint2 r;
    r.x = *reinterpret_cast<const unsigned int*>(&ab);
    r.y = *reinterpret_cast<const unsigned int*>(&cz);
    return r;
}

__device__ __forceinline__ void fmacc(uint2 v, float w,
                                      float& a0, float& a1, float& a2) {
    __half2 ab = *reinterpret_cast<const __half2*>(&v.x);
    __half2 cz = *reinterpret_cast<const __half2*>(&v.y);
    // (float)half * f32 + f32 acc -> v_fma_mix_f32
    a0 += __half2float(__low2half(ab))  * w;
    a1 += __half2float(__high2half(ab)) * w;
    a2 += __half2float(__low2half(cz))  * w;
}

__global__ __launch_bounds__(256, 4) void dsepconv_kernel(
    const float* __restrict__ inp,   // (B, C, HI, WI)
    const float* __restrict__ vert,  // (B, F, HO, WO)
    const float* __restrict__ horz,  // (B, F, HO, WO)
    const float* __restrict__ offX,  // -> py (vertical), per reference
    const float* __restrict__ offY,  // -> px (horizontal), per reference
    const float* __restrict__ mask,  // (B, F*F, HO, WO)
    float* __restrict__ out)         // (B, C, HO, WO)
{
    __shared__ uint2 tileq[TROWS * TSTRIDE];  // 22,648 B
    __shared__ float red[2][3][128];          // 3,072 B: half-1 partials

    const int tid  = threadIdx.x;
    const int lane = tid & 63;
    const int wave = tid >> 6;                 // 0..3
    const int wrow = wave >> 1;                // 0..1: y-row in patch
    const int half = wave & 1;                 // 0..1: tap half

    // Grid: bx = b*256 + yblk*2 + xblk ; patch origin (y0, x0)
    const int bx   = blockIdx.x;
    const int x0   = (bx & 1) * 128;
    const int y0   = ((bx >> 1) & 127) * 2;
    const int b    = bx >> 8;

    const float* in0 = inp + (size_t)b * C * PI;
    const float* in1 = in0 + PI;
    const float* in2 = in1 + PI;

    const int x   = x0 + 2 * lane;             // even; this thread: x, x+1
    const int y   = y0 + wrow;
    const int pix = y * WO + x;

    const float* offXb = offX + (size_t)b * FF * P + pix;
    const float* offYb = offY + (size_t)b * FF * P + pix;
    const float* maskb = mask + (size_t)b * FF * P + pix;
    const float* vb    = vert + (size_t)b * F * P + pix;
    const float* hb    = horz + (size_t)b * F * P + pix;

    const int k0 = half ? 12 : 0;
    const int k1 = half ? 25 : 12;

    // ---- Prefetch first tap's streams (drained by the staging barrier) ----
    float2 oy, ox, m, h, v;
    {
        const int i = k0 / F, j = k0 - (k0 / F) * F;
        oy = ld2(offYb + (size_t)k0 * P);
        ox = ld2(offXb + (size_t)k0 * P);
        m  = ld2(maskb + (size_t)k0 * P);
        h  = ld2(hb + (size_t)j * P);
        v  = ld2(vb + (size_t)i * P);
    }

    // ---- Stage tile: rows [y0-7, y0+11], cols [x0-7, x0+137] ----
    const int ry0 = y0 - 7;
    const int cx0 = x0 - 7;
#pragma unroll 1
    for (int e = tid; e < TN; e += 256) {
        int trow = e / TCOLS;
        int tcol = e - trow * TCOLS;
        int gy = min(max(ry0 + trow, 0), HI - 1);
        int gx = min(max(cx0 + tcol, 0), WI - 1);
        int g = gy * WI + gx;
        tileq[trow * TSTRIDE + tcol] = pack3(in0[g], in1[g], in2[g]);
    }
    __syncthreads();   // vmcnt(0) drain also completes the stream prefetch

    float acc0a = 0.f, acc1a = 0.f, acc2a = 0.f;
    float acc0b = 0.f, acc1b = 0.f, acc2b = 0.f;

#pragma unroll 1
    for (int k = k0; k < k1; ++k) {
        const int i = k / F;
        const int j = k - i * F;

        // ---- issue NEXT tap's streams (float2, overlap with compute) ----
        const int kn  = (k + 1 < k1) ? k + 1 : k;
        const int in_ = kn / F;
        const int jn  = kn - in_ * F;
        float2 oy_n = ld2(offYb + (size_t)kn * P);
        float2 ox_n = ld2(offXb + (size_t)kn * P);
        float2 m_n  = ld2(maskb + (size_t)kn * P);
        float2 h_n  = ld2(hb + (size_t)jn * P);
        float2 v_n  = ld2(vb + (size_t)in_ * P);

        // ---- coords, pixel A (x) and B (x+1) ----
        // px = clip(offY + x + j - half + 1, 0, WI-1); half = 2
        float pya = fminf(fmaxf(ox.x + (float)(y + i - 1), 0.0f), (float)(HI - 1));
        float pyb = fminf(fmaxf(ox.y + (float)(y + i - 1), 0.0f), (float)(HI - 1));
        float pxa = fminf(fmaxf(oy.x + (float)(x + j - 1), 0.0f), (float)(WI - 1));
        float pxb = fminf(fmaxf(oy.y + (float)(x + j), 0.0f), (float)(WI - 1));

        float lfa = floorf(pxa), tfa = floorf(pya);
        float lfb = floorf(pxb), tfb = floorf(pyb);
        int la = (int)lfa, ta = (int)tfa;
        int lb = (int)lfb, tb = (int)tfb;
        float wxa = 1.0f - (pxa - lfa), wya = 1.0f - (pya - tfa);
        float wxb = 1.0f - (pxb - lfb), wyb = 1.0f - (pyb - tfb);

        int lta = ta - ry0, lla = la - cx0;
        int ltb = tb - ry0, llb = lb - cx0;
        bool oka = ((unsigned)lta <= TROWS - 2) & ((unsigned)lla <= TCOLS - 2);
        bool okb = ((unsigned)ltb <= TROWS - 2) & ((unsigned)llb <= TCOLS - 2);

        int aa = min(max(lta * TSTRIDE + lla, 0), AMAX);
        int ab = min(max(ltb * TSTRIDE + llb, 0), AMAX);

        // ---- 8 gathers issue together; FMAs follow ----
        uint2 ga0 = tileq[aa];
        uint2 ga1 = tileq[aa + 1];
        uint2 ga2 = tileq[aa + TSTRIDE];
        uint2 ga3 = tileq[aa + TSTRIDE + 1];
        uint2 gb0 = tileq[ab];
        uint2 gb1 = tileq[ab + 1];
        uint2 gb2 = tileq[ab + TSTRIDE];
        uint2 gb3 = tileq[ab + TSTRIDE + 1];

        // rare fallback: offset beyond tile margin (~1e-9/sample)
        if (__any(!(oka & okb))) {
            if (!oka) {
                int r  = min(la + 1, WI - 1);
                int bt = min(ta + 1, HI - 1);
                int o0 = ta * WI + la, o1 = ta * WI + r;
                int o2 = bt * WI + la, o3 = bt * WI + r;
                ga0 = pack3(in0[o0], in1[o0], in2[o0]);
                ga1 = pack3(in0[o1], in1[o1], in2[o1]);
                ga2 = pack3(in0[o2], in1[o2], in2[o2]);
                ga3 = pack3(in0[o3], in1[o3], in2[o3]);
            }
            if (!okb) {
                int r  = min(lb + 1, WI - 1);
                int bt = min(tb + 1, HI - 1);
                int o0 = tb * WI + lb, o1 = tb * WI + r;
                int o2 = bt * WI + lb, o3 = bt * WI + r;
                gb0 = pack3(in0[o0], in1[o0], in2[o0]);
                gb1 = pack3(in0[o1], in1[o1], in2[o1]);
                gb2 = pack3(in0[o2], in1[o2], in2[o2]);
                gb3 = pack3(in0[o3], in1[o3], in2[o3]);
            }
        }

        // Bilinear identity: clamped edge => r/bottom weights exactly 0.
        float wA   = v.x * h.x * m.x;
        float wywA = wya * wA;
        float wbwA = wA - wywA;
        float wtlA = wxa * wywA;
        float wtrA = wywA - wtlA;
        float wblA = wxa * wbwA;
        float wbrA = wbwA - wblA;

        float wB   = v.y * h.y * m.y;
        float wywB = wyb * wB;
        float wbwB = wB - wywB;
        float wtlB = wxb * wywB;
        float wtrB = wywB - wtlB;
        float wblB = wxb * wbwB;
        float wbrB = wbwB - wblB;

        fmacc(ga0, wtlA, acc0a, acc1a, acc2a);
        fmacc(ga1, wtrA, acc0a, acc1a, acc2a);
        fmacc(ga2, wblA, acc0a, acc1a, acc2a);
        fmacc(ga3, wbrA, acc0a, acc1a, acc2a);
        fmacc(gb0, wtlB, acc0b, acc1b, acc2b);
        fmacc(gb1, wtrB, acc0b, acc1b, acc2b);
        fmacc(gb2, wblB, acc0b, acc1b, acc2b);
        fmacc(gb3, wbrB, acc0b, acc1b, acc2b);

        // ---- rotate stream pipeline ----
        oy = oy_n; ox = ox_n; m = m_n; h = h_n; v = v_n;
    }

    // ---- Combine the two tap-halves per row (float2 traffic) ----
    if (half) {
        *reinterpret_cast<float2*>(&red[wrow][0][2 * lane]) = make_float2(acc0a, acc0b);
        *reinterpret_cast<float2*>(&red[wrow][1][2 * lane]) = make_float2(acc1a, acc1b);
        *reinterpret_cast<float2*>(&red[wrow][2][2 * lane]) = make_float2(acc2a, acc2b);
    }
    __syncthreads();

    if (!half) {
        float* ob = out + (size_t)b * C * P + pix;
        float2 r0 = *reinterpret_cast<const float2*>(&red[wrow][0][2 * lane]);
        float2 r1 = *reinterpret_cast<const float2*>(&red[wrow][1][2 * lane]);
        float2 r2 = *reinterpret_cast<const float2*>(&red[wrow][2][2 * lane]);
        *reinterpret_cast<float2*>(&ob[0])     = make_float2(acc0a + r0.x, acc0b + r0.y);
        *reinterpret_cast<float2*>(&ob[P])     = make_float2(acc1a + r1.x, acc1b + r1.y);
        *reinterpret_cast<float2*>(&ob[2 * P]) = make_float2(acc2a + r2.x, acc2b + r2.y);
    }
}

extern "C" void kernel_launch(void* const* d_in, const int* in_sizes, int n_in,
                              void* d_out, int out_size, void* d_ws, size_t ws_size,
                              hipStream_t stream) {
    const float* inp  = (const float*)d_in[0];
    const float* vert = (const float*)d_in[1];
    const float* horz = (const float*)d_in[2];
    const float* offX = (const float*)d_in[3];
    const float* offY = (const float*)d_in[4];
    const float* mask = (const float*)d_in[5];
    float* out = (float*)d_out;

    // grid: B * (HO/2) * (WO/128) = 4 * 128 * 2 = 1024 blocks, 256 thr each
    dim3 block(256);
    dim3 grid(B * (HO / 2) * (WO / 128));
    dsepconv_kernel<<<grid, block, 0, stream>>>(inp, vert, horz, offX, offY, mask, out);
}